// Round 14
// baseline (410.639 us; speedup 1.0000x reference)
//
#include <hip/hip_runtime.h>

#define IN_DIM 784
#define HID 128
#define NSTEP 16
#define BATCH 16384

typedef float v2f __attribute__((ext_vector_type(2)));
typedef float v4f __attribute__((ext_vector_type(4)));
typedef unsigned long long ull;

// ws float layout (all fp32):
constexpr int W0T_OFF = 0;                    // W0t[k*128+j] = W0[j][k]*r0   (784x128)
constexpr int W1T_OFF = W0T_OFF + IN_DIM*HID; // 100352: W1t (128x128)
constexpr int W2T_OFF = W1T_OFF + HID*HID;    // 116736: W2t (128x128)
constexpr int W3T_OFF = W2T_OFF + HID*HID;    // 133120: W3t[k*784+o] = W3[o][k]*r3 (128x784)
constexpr int B0_OFF  = W3T_OFF + HID*IN_DIM; // 233472
constexpr int B1_OFF  = B0_OFF + HID;
constexpr int B2_OFF  = B1_OFF + HID;
constexpr int B3_OFF  = B2_OFF + HID;
constexpr int WS_FLOATS = B3_OFF + IN_DIM;    // 234640 floats = 938 KB

// chunking of W0t for LDS staging
constexpr int CHUNK_COLS = 32;                // 32 cols x 128 floats = 16 KB
constexpr int CHUNK_F    = CHUNK_COLS * HID;  // 4096 floats
constexpr int NCHUNK     = 25;                // 24 full + 1 half (cols 768..783)

constexpr int TPB   = 256;                    // 4 waves = 4 samples per block (R4 geometry)
constexpr int WAVES = TPB / 64;

__global__ __launch_bounds__(256) void prep_kernel(
    const float* __restrict__ W0, const float* __restrict__ b0,
    const float* __restrict__ W1, const float* __restrict__ b1,
    const float* __restrict__ W2, const float* __restrict__ b2,
    const float* __restrict__ W3, const float* __restrict__ b3,
    const float* __restrict__ ib0, const float* __restrict__ ob0,
    const float* __restrict__ ib1, const float* __restrict__ ob1,
    const float* __restrict__ ib2, const float* __restrict__ ob2,
    const float* __restrict__ ib3, const float* __restrict__ ob3,
    float* __restrict__ ws)
{
    int idx = blockIdx.x * 256 + threadIdx.x;
    if (idx >= WS_FLOATS) return;
    float r0 = (ib0[1] - ib0[0]) / (ob0[1] - ob0[0]);
    float r1 = (ib1[1] - ib1[0]) / (ob1[1] - ob1[0]);
    float r2 = (ib2[1] - ib2[0]) / (ob2[1] - ob2[0]);
    float r3 = (ib3[1] - ib3[0]) / (ob3[1] - ob3[0]);
    if (idx < W1T_OFF) {
        int t = idx;            int k = t >> 7, j = t & 127;
        ws[idx] = W0[j * IN_DIM + k] * r0;
    } else if (idx < W2T_OFF) {
        int t = idx - W1T_OFF;  int k = t >> 7, j = t & 127;
        ws[idx] = W1[j * HID + k] * r1;
    } else if (idx < W3T_OFF) {
        int t = idx - W2T_OFF;  int k = t >> 7, j = t & 127;
        ws[idx] = W2[j * HID + k] * r2;
    } else if (idx < B0_OFF) {
        int t = idx - W3T_OFF;  int k = t / IN_DIM, o = t % IN_DIM;
        ws[idx] = W3[o * HID + k] * r3;
    } else if (idx < B1_OFF) ws[idx] = b0[idx - B0_OFF] * r0;
    else if (idx < B2_OFF)   ws[idx] = b1[idx - B1_OFF] * r1;
    else if (idx < B3_OFF)   ws[idx] = b2[idx - B2_OFF] * r2;
    else                     ws[idx] = b3[idx - B3_OFF] * r3;
}

__global__ __launch_bounds__(TPB) void snn_main(
    const float* __restrict__ feat,
    const float* __restrict__ ws,
    const float* __restrict__ ib0,
    const float* __restrict__ ob3,
    float* __restrict__ out)
{
    __shared__ float smem[2 * CHUNK_F];       // 32 KB double buffer

    const int tid  = threadIdx.x;
    const int lane = tid & 63;
    const int wid  = tid >> 6;
    const int sample = blockIdx.x * WAVES + wid;

    const float* W0t = ws + W0T_OFF;
    const float* W1t = ws + W1T_OFF;
    const float* W2t = ws + W2T_OFF;
    const float* W3t = ws + W3T_OFF;
    const float* frow = feat + (size_t)sample * IN_DIM;

    float edge[16];
#pragma unroll
    for (int e = 0; e < 16; ++e) edge[e] = ib0[e + 1];

    // ---- stage chunk 0 (256 threads x 4 float4 = 4096 floats) ----
    {
        const float4* g4 = (const float4*)W0t;
        float4* lb = (float4*)smem;
#pragma unroll
        for (int i = 0; i < 4; ++i) lb[i * TPB + tid] = g4[i * TPB + tid];
    }
    __syncthreads();

    // ---- bucket build: C[mv-1] = sum of W0t columns whose pixel level == mv ----
    v2f C[16];
#pragma unroll
    for (int mv = 0; mv < 16; ++mv) C[mv] = (v2f)(0.f);

    for (int c = 0; c < NCHUNK; ++c) {
        // prefetch next chunk into registers (overlaps consumption of chunk c).
        // unconditional: for c==24 this reads into the W1t region (valid memory), discarded.
        float4 rg0, rg1, rg2, rg3;
        {
            const float4* g4 = (const float4*)W0t + (size_t)(c + 1) * (CHUNK_F / 4);
            rg0 = g4[0 * TPB + tid];
            rg1 = g4[1 * TPB + tid];
            rg2 = g4[2 * TPB + tid];
            rg3 = g4[3 * TPB + tid];
        }

        // digitize this chunk's 32 columns (lanes 32-63 duplicate lanes 0-31)
        int col = c * CHUNK_COLS + (lane & 31);
        bool valid = col < IN_DIM;
        float x = frow[valid ? col : 0];
        int mm = 0;
#pragma unroll
        for (int e = 0; e < 16; ++e) mm += (x >= edge[e]) ? 1 : 0;
        if (!valid) mm = -1;

        // consume chunk c from LDS (4-peeled, 2 acc chains, packed adds)
        const v2f* bufp = (const v2f*)(smem + (c & 1) * CHUNK_F);
#pragma unroll
        for (int mv = 1; mv <= 16; ++mv) {
            unsigned mk = (unsigned)__ballot(mm == mv);
            v2f ca = (v2f)(0.f), cb = (v2f)(0.f);
            while (mk) {
                int b0 = __builtin_ctz(mk); mk &= mk - 1;
                v2f w0 = bufp[b0 * 64 + lane];
                if (mk) {
                    int b1 = __builtin_ctz(mk); mk &= mk - 1;
                    v2f w1 = bufp[b1 * 64 + lane];
                    if (mk) {
                        int b2 = __builtin_ctz(mk); mk &= mk - 1;
                        v2f w2 = bufp[b2 * 64 + lane];
                        if (mk) {
                            int b3i = __builtin_ctz(mk); mk &= mk - 1;
                            v2f w3 = bufp[b3i * 64 + lane];
                            cb += w3;
                        }
                        ca += w2;
                    }
                    cb += w1;
                }
                ca += w0;
            }
            C[mv - 1] += ca + cb;
        }

        if (c + 1 < NCHUNK) {
            float4* lb = (float4*)(smem + ((c + 1) & 1) * CHUNK_F);
            lb[0 * TPB + tid] = rg0;
            lb[1 * TPB + tid] = rg1;
            lb[2 * TPB + tid] = rg2;
            lb[3 * TPB + tid] = rg3;
        }
        __syncthreads();
    }

    // ---- persistent membrane state ----
    v2f t0 = ((const v2f*)(ws + B0_OFF))[lane];
    v2f t1 = ((const v2f*)(ws + B1_OFF))[lane];
    v2f t2 = ((const v2f*)(ws + B2_OFF))[lane];
    v4f t3[4], cnt[4];
    {
        const v4f* b3v = (const v4f*)(ws + B3_OFF);
#pragma unroll
        for (int r = 0; r < 3; ++r) t3[r] = b3v[r * 64 + lane];
        t3[3] = (v4f)(0.f);
        if (lane < 4) t3[3] = b3v[192 + lane];
#pragma unroll
        for (int r = 0; r < 4; ++r) cnt[r] = (v4f)(0.f);
    }

    // ---- 16-step recurrence (runtime loop: keeps code small, I$-resident) ----
    for (int s = 1; s <= NSTEP; ++s) {
        // input current: sum of active bucket vectors (scalar-uniform branches)
#pragma unroll
        for (int mv = 1; mv <= 16; ++mv) {
            if (((s * mv) & 15) < mv) t0 += C[mv - 1];
        }
        // ---- layer0 spikes -> layer1 (4-peeled) ----
        {
            bool px = (t0.x >= 1.0f), py = (t0.y >= 1.0f);
            ull mx = __ballot(px);
            ull my = __ballot(py);
            if (px) t0.x -= 1.0f;
            if (py) t0.y -= 1.0f;
            v2f ca = (v2f)(0.f), cb = (v2f)(0.f);
            while (mx) {
                int b0 = __builtin_amdgcn_readfirstlane(__builtin_ctzll(mx)); mx &= mx - 1;
                v2f w0 = ((const v2f*)(W1t + (2 * b0) * HID))[lane];
                if (mx) {
                    int b1 = __builtin_amdgcn_readfirstlane(__builtin_ctzll(mx)); mx &= mx - 1;
                    v2f w1 = ((const v2f*)(W1t + (2 * b1) * HID))[lane];
                    if (mx) {
                        int b2 = __builtin_amdgcn_readfirstlane(__builtin_ctzll(mx)); mx &= mx - 1;
                        v2f w2 = ((const v2f*)(W1t + (2 * b2) * HID))[lane];
                        if (mx) {
                            int b3i = __builtin_amdgcn_readfirstlane(__builtin_ctzll(mx)); mx &= mx - 1;
                            v2f w3 = ((const v2f*)(W1t + (2 * b3i) * HID))[lane];
                            cb += w3;
                        }
                        ca += w2;
                    }
                    cb += w1;
                }
                ca += w0;
            }
            while (my) {
                int b0 = __builtin_amdgcn_readfirstlane(__builtin_ctzll(my)); my &= my - 1;
                v2f w0 = ((const v2f*)(W1t + (2 * b0 + 1) * HID))[lane];
                if (my) {
                    int b1 = __builtin_amdgcn_readfirstlane(__builtin_ctzll(my)); my &= my - 1;
                    v2f w1 = ((const v2f*)(W1t + (2 * b1 + 1) * HID))[lane];
                    if (my) {
                        int b2 = __builtin_amdgcn_readfirstlane(__builtin_ctzll(my)); my &= my - 1;
                        v2f w2 = ((const v2f*)(W1t + (2 * b2 + 1) * HID))[lane];
                        if (my) {
                            int b3i = __builtin_amdgcn_readfirstlane(__builtin_ctzll(my)); my &= my - 1;
                            v2f w3 = ((const v2f*)(W1t + (2 * b3i + 1) * HID))[lane];
                            cb += w3;
                        }
                        ca += w2;
                    }
                    cb += w1;
                }
                ca += w0;
            }
            t1 += ca + cb;
        }
        // ---- layer1 spikes -> layer2 (4-peeled) ----
        {
            bool px = (t1.x >= 1.0f), py = (t1.y >= 1.0f);
            ull mx = __ballot(px);
            ull my = __ballot(py);
            if (px) t1.x -= 1.0f;
            if (py) t1.y -= 1.0f;
            v2f ca = (v2f)(0.f), cb = (v2f)(0.f);
            while (mx) {
                int b0 = __builtin_amdgcn_readfirstlane(__builtin_ctzll(mx)); mx &= mx - 1;
                v2f w0 = ((const v2f*)(W2t + (2 * b0) * HID))[lane];
                if (mx) {
                    int b1 = __builtin_amdgcn_readfirstlane(__builtin_ctzll(mx)); mx &= mx - 1;
                    v2f w1 = ((const v2f*)(W2t + (2 * b1) * HID))[lane];
                    if (mx) {
                        int b2 = __builtin_amdgcn_readfirstlane(__builtin_ctzll(mx)); mx &= mx - 1;
                        v2f w2 = ((const v2f*)(W2t + (2 * b2) * HID))[lane];
                        if (mx) {
                            int b3i = __builtin_amdgcn_readfirstlane(__builtin_ctzll(mx)); mx &= mx - 1;
                            v2f w3 = ((const v2f*)(W2t + (2 * b3i) * HID))[lane];
                            cb += w3;
                        }
                        ca += w2;
                    }
                    cb += w1;
                }
                ca += w0;
            }
            while (my) {
                int b0 = __builtin_amdgcn_readfirstlane(__builtin_ctzll(my)); my &= my - 1;
                v2f w0 = ((const v2f*)(W2t + (2 * b0 + 1) * HID))[lane];
                if (my) {
                    int b1 = __builtin_amdgcn_readfirstlane(__builtin_ctzll(my)); my &= my - 1;
                    v2f w1 = ((const v2f*)(W2t + (2 * b1 + 1) * HID))[lane];
                    if (my) {
                        int b2 = __builtin_amdgcn_readfirstlane(__builtin_ctzll(my)); my &= my - 1;
                        v2f w2 = ((const v2f*)(W2t + (2 * b2 + 1) * HID))[lane];
                        if (my) {
                            int b3i = __builtin_amdgcn_readfirstlane(__builtin_ctzll(my)); my &= my - 1;
                            v2f w3 = ((const v2f*)(W2t + (2 * b3i + 1) * HID))[lane];
                            cb += w3;
                        }
                        ca += w2;
                    }
                    cb += w1;
                }
                ca += w0;
            }
            t2 += ca + cb;
        }
        // ---- layer2 spikes -> layer3 (2-peeled spikes x 4-wide loads) ----
        {
            bool px = (t2.x >= 1.0f), py = (t2.y >= 1.0f);
            ull mx = __ballot(px);
            ull my = __ballot(py);
            if (px) t2.x -= 1.0f;
            if (py) t2.y -= 1.0f;
            while (mx) {
                int b0 = __builtin_amdgcn_readfirstlane(__builtin_ctzll(mx)); mx &= mx - 1;
                const v4f* c0 = (const v4f*)(W3t + (2 * b0) * IN_DIM);
                v4f x0 = c0[lane], x1 = c0[64 + lane], x2 = c0[128 + lane];
                v4f x3 = c0[192 + (lane & 3)];
                if (mx) {
                    int b1 = __builtin_amdgcn_readfirstlane(__builtin_ctzll(mx)); mx &= mx - 1;
                    const v4f* c1 = (const v4f*)(W3t + (2 * b1) * IN_DIM);
                    v4f y0 = c1[lane], y1 = c1[64 + lane], y2 = c1[128 + lane];
                    v4f y3 = c1[192 + (lane & 3)];
                    t3[0] += y0; t3[1] += y1; t3[2] += y2;
                    if (lane < 4) t3[3] += y3;
                }
                t3[0] += x0; t3[1] += x1; t3[2] += x2;
                if (lane < 4) t3[3] += x3;
            }
            while (my) {
                int b0 = __builtin_amdgcn_readfirstlane(__builtin_ctzll(my)); my &= my - 1;
                const v4f* c0 = (const v4f*)(W3t + (2 * b0 + 1) * IN_DIM);
                v4f x0 = c0[lane], x1 = c0[64 + lane], x2 = c0[128 + lane];
                v4f x3 = c0[192 + (lane & 3)];
                if (my) {
                    int b1 = __builtin_amdgcn_readfirstlane(__builtin_ctzll(my)); my &= my - 1;
                    const v4f* c1 = (const v4f*)(W3t + (2 * b1 + 1) * IN_DIM);
                    v4f y0 = c1[lane], y1 = c1[64 + lane], y2 = c1[128 + lane];
                    v4f y3 = c1[192 + (lane & 3)];
                    t3[0] += y0; t3[1] += y1; t3[2] += y2;
                    if (lane < 4) t3[3] += y3;
                }
                t3[0] += x0; t3[1] += x1; t3[2] += x2;
                if (lane < 4) t3[3] += x3;
            }
        }
        // ---- layer3 spike + output count ----
#pragma unroll
        for (int r = 0; r < 4; ++r) {
            if (t3[r].x >= 1.0f) { t3[r].x -= 1.0f; cnt[r].x += 1.0f; }
            if (t3[r].y >= 1.0f) { t3[r].y -= 1.0f; cnt[r].y += 1.0f; }
            if (t3[r].z >= 1.0f) { t3[r].z -= 1.0f; cnt[r].z += 1.0f; }
            if (t3[r].w >= 1.0f) { t3[r].w -= 1.0f; cnt[r].w += 1.0f; }
        }
    }

    // ---- reconstruct: spikes * h_out3 ----
    const float h = ob3[1] - ob3[0];
    v4f* orow = (v4f*)(out + (size_t)sample * IN_DIM);
#pragma unroll
    for (int r = 0; r < 3; ++r)
        orow[r * 64 + lane] = cnt[r] * h;
    if (lane < 4)
        orow[192 + lane] = cnt[3] * h;
}

extern "C" void kernel_launch(void* const* d_in, const int* in_sizes, int n_in,
                              void* d_out, int out_size, void* d_ws, size_t ws_size,
                              hipStream_t stream)
{
    const float* feat = (const float*)d_in[0];
    const float* W0  = (const float*)d_in[1];
    const float* b0  = (const float*)d_in[2];
    const float* W1  = (const float*)d_in[3];
    const float* b1  = (const float*)d_in[4];
    const float* W2  = (const float*)d_in[5];
    const float* b2  = (const float*)d_in[6];
    const float* W3  = (const float*)d_in[7];
    const float* b3  = (const float*)d_in[8];
    const float* ib0 = (const float*)d_in[9];
    const float* ob0 = (const float*)d_in[10];
    const float* ib1 = (const float*)d_in[11];
    const float* ob1 = (const float*)d_in[12];
    const float* ib2 = (const float*)d_in[13];
    const float* ob2 = (const float*)d_in[14];
    const float* ib3 = (const float*)d_in[15];
    const float* ob3 = (const float*)d_in[16];
    float* ws  = (float*)d_ws;
    float* op  = (float*)d_out;

    prep_kernel<<<(WS_FLOATS + 255) / 256, 256, 0, stream>>>(
        W0, b0, W1, b1, W2, b2, W3, b3,
        ib0, ob0, ib1, ob1, ib2, ob2, ib3, ob3, ws);

    snn_main<<<BATCH / WAVES, TPB, 0, stream>>>(feat, ws, ib0, ob3, op);
}

// Round 15
// 409.346 us; speedup vs baseline: 1.0032x; 1.0032x over previous
//
#include <hip/hip_runtime.h>

#define IN_DIM 784
#define HID 128
#define NSTEP 16
#define BATCH 16384

typedef float v2f __attribute__((ext_vector_type(2)));
typedef float v4f __attribute__((ext_vector_type(4)));
typedef unsigned long long ull;

// ws float layout (all fp32):
constexpr int W0T_OFF = 0;                    // W0t[k*128+j] = W0[j][k]*r0   (784x128)
constexpr int W1T_OFF = W0T_OFF + IN_DIM*HID; // 100352: W1t (128x128)
constexpr int W2T_OFF = W1T_OFF + HID*HID;    // 116736: W2t (128x128)
constexpr int W3T_OFF = W2T_OFF + HID*HID;    // 133120: W3t[k*784+o] = W3[o][k]*r3 (128x784)
constexpr int B0_OFF  = W3T_OFF + HID*IN_DIM; // 233472
constexpr int B1_OFF  = B0_OFF + HID;
constexpr int B2_OFF  = B1_OFF + HID;
constexpr int B3_OFF  = B2_OFF + HID;
constexpr int WS_FLOATS = B3_OFF + IN_DIM;    // 234640 floats = 938 KB

// chunking of W0t for LDS staging
constexpr int CHUNK_COLS = 32;                // 32 cols x 128 floats = 16 KB
constexpr int CHUNK_F    = CHUNK_COLS * HID;  // 4096 floats
constexpr int NCHUNK     = 25;                // 24 full + 1 half (cols 768..783)

constexpr int TPB   = 256;                    // 4 waves = 4 samples per block (R4 geometry)
constexpr int WAVES = TPB / 64;

__global__ __launch_bounds__(256) void prep_kernel(
    const float* __restrict__ W0, const float* __restrict__ b0,
    const float* __restrict__ W1, const float* __restrict__ b1,
    const float* __restrict__ W2, const float* __restrict__ b2,
    const float* __restrict__ W3, const float* __restrict__ b3,
    const float* __restrict__ ib0, const float* __restrict__ ob0,
    const float* __restrict__ ib1, const float* __restrict__ ob1,
    const float* __restrict__ ib2, const float* __restrict__ ob2,
    const float* __restrict__ ib3, const float* __restrict__ ob3,
    float* __restrict__ ws)
{
    int idx = blockIdx.x * 256 + threadIdx.x;
    if (idx >= WS_FLOATS) return;
    float r0 = (ib0[1] - ib0[0]) / (ob0[1] - ob0[0]);
    float r1 = (ib1[1] - ib1[0]) / (ob1[1] - ob1[0]);
    float r2 = (ib2[1] - ib2[0]) / (ob2[1] - ob2[0]);
    float r3 = (ib3[1] - ib3[0]) / (ob3[1] - ob3[0]);
    if (idx < W1T_OFF) {
        int t = idx;            int k = t >> 7, j = t & 127;
        ws[idx] = W0[j * IN_DIM + k] * r0;
    } else if (idx < W2T_OFF) {
        int t = idx - W1T_OFF;  int k = t >> 7, j = t & 127;
        ws[idx] = W1[j * HID + k] * r1;
    } else if (idx < W3T_OFF) {
        int t = idx - W2T_OFF;  int k = t >> 7, j = t & 127;
        ws[idx] = W2[j * HID + k] * r2;
    } else if (idx < B0_OFF) {
        int t = idx - W3T_OFF;  int k = t / IN_DIM, o = t % IN_DIM;
        ws[idx] = W3[o * HID + k] * r3;
    } else if (idx < B1_OFF) ws[idx] = b0[idx - B0_OFF] * r0;
    else if (idx < B2_OFF)   ws[idx] = b1[idx - B1_OFF] * r1;
    else if (idx < B3_OFF)   ws[idx] = b2[idx - B2_OFF] * r2;
    else                     ws[idx] = b3[idx - B3_OFF] * r3;
}

__global__ __launch_bounds__(TPB) void snn_main(
    const float* __restrict__ feat,
    const float* __restrict__ ws,
    const float* __restrict__ ib0,
    const float* __restrict__ ob3,
    float* __restrict__ out)
{
    __shared__ float smem[2 * CHUNK_F];       // 32 KB double buffer

    const int tid  = threadIdx.x;
    const int lane = tid & 63;
    const int wid  = tid >> 6;
    const int sample = blockIdx.x * WAVES + wid;

    const float* W0t = ws + W0T_OFF;
    const float* W1t = ws + W1T_OFF;
    const float* W2t = ws + W2T_OFF;
    const float* W3t = ws + W3T_OFF;
    const float* frow = feat + (size_t)sample * IN_DIM;

    float edge[16];
#pragma unroll
    for (int e = 0; e < 16; ++e) edge[e] = ib0[e + 1];

    // ---- stage chunk 0 (256 threads x 4 float4 = 4096 floats) ----
    {
        const float4* g4 = (const float4*)W0t;
        float4* lb = (float4*)smem;
#pragma unroll
        for (int i = 0; i < 4; ++i) lb[i * TPB + tid] = g4[i * TPB + tid];
    }
    __syncthreads();

    // ---- bucket build: C[mv-1] = sum of W0t columns whose pixel level == mv ----
    v2f C[16];
#pragma unroll
    for (int mv = 0; mv < 16; ++mv) C[mv] = (v2f)(0.f);

    for (int c = 0; c < NCHUNK; ++c) {
        // prefetch next chunk into registers (overlaps consumption of chunk c).
        // unconditional: for c==24 this reads into the W1t region (valid memory), discarded.
        float4 rg0, rg1, rg2, rg3;
        {
            const float4* g4 = (const float4*)W0t + (size_t)(c + 1) * (CHUNK_F / 4);
            rg0 = g4[0 * TPB + tid];
            rg1 = g4[1 * TPB + tid];
            rg2 = g4[2 * TPB + tid];
            rg3 = g4[3 * TPB + tid];
        }

        // digitize this chunk's 32 columns (lanes 32-63 duplicate lanes 0-31)
        int col = c * CHUNK_COLS + (lane & 31);
        bool valid = col < IN_DIM;
        float x = frow[valid ? col : 0];
        int mm = 0;
#pragma unroll
        for (int e = 0; e < 16; ++e) mm += (x >= edge[e]) ? 1 : 0;
        if (!valid) mm = -1;

        // consume chunk c from LDS (4-peeled, 2 acc chains, packed adds)
        const v2f* bufp = (const v2f*)(smem + (c & 1) * CHUNK_F);
#pragma unroll
        for (int mv = 1; mv <= 16; ++mv) {
            unsigned mk = (unsigned)__ballot(mm == mv);
            v2f ca = (v2f)(0.f), cb = (v2f)(0.f);
            while (mk) {
                int b0 = __builtin_ctz(mk); mk &= mk - 1;
                v2f w0 = bufp[b0 * 64 + lane];
                if (mk) {
                    int b1 = __builtin_ctz(mk); mk &= mk - 1;
                    v2f w1 = bufp[b1 * 64 + lane];
                    if (mk) {
                        int b2 = __builtin_ctz(mk); mk &= mk - 1;
                        v2f w2 = bufp[b2 * 64 + lane];
                        if (mk) {
                            int b3i = __builtin_ctz(mk); mk &= mk - 1;
                            v2f w3 = bufp[b3i * 64 + lane];
                            cb += w3;
                        }
                        ca += w2;
                    }
                    cb += w1;
                }
                ca += w0;
            }
            C[mv - 1] += ca + cb;
        }

        if (c + 1 < NCHUNK) {
            float4* lb = (float4*)(smem + ((c + 1) & 1) * CHUNK_F);
            lb[0 * TPB + tid] = rg0;
            lb[1 * TPB + tid] = rg1;
            lb[2 * TPB + tid] = rg2;
            lb[3 * TPB + tid] = rg3;
        }
        __syncthreads();
    }

    // ---- persistent membrane state ----
    v2f t0 = ((const v2f*)(ws + B0_OFF))[lane];
    v2f t1 = ((const v2f*)(ws + B1_OFF))[lane];
    v2f t2 = ((const v2f*)(ws + B2_OFF))[lane];
    v4f t3[4], cnt[4];
    {
        const v4f* b3v = (const v4f*)(ws + B3_OFF);
#pragma unroll
        for (int r = 0; r < 3; ++r) t3[r] = b3v[r * 64 + lane];
        t3[3] = (v4f)(0.f);
        if (lane < 4) t3[3] = b3v[192 + lane];
#pragma unroll
        for (int r = 0; r < 4; ++r) cnt[r] = (v4f)(0.f);
    }

    // ---- 16-step recurrence (runtime loop: keeps code small, I$-resident) ----
    for (int s = 1; s <= NSTEP; ++s) {
        // input current: sum of active bucket vectors (scalar-uniform branches)
#pragma unroll
        for (int mv = 1; mv <= 16; ++mv) {
            if (((s * mv) & 15) < mv) t0 += C[mv - 1];
        }
        // ---- layer0 spikes -> layer1 (4-peeled) ----
        {
            bool px = (t0.x >= 1.0f), py = (t0.y >= 1.0f);
            ull mx = __ballot(px);
            ull my = __ballot(py);
            if (px) t0.x -= 1.0f;
            if (py) t0.y -= 1.0f;
            v2f ca = (v2f)(0.f), cb = (v2f)(0.f);
            while (mx) {
                int b0 = __builtin_amdgcn_readfirstlane(__builtin_ctzll(mx)); mx &= mx - 1;
                v2f w0 = ((const v2f*)(W1t + (2 * b0) * HID))[lane];
                if (mx) {
                    int b1 = __builtin_amdgcn_readfirstlane(__builtin_ctzll(mx)); mx &= mx - 1;
                    v2f w1 = ((const v2f*)(W1t + (2 * b1) * HID))[lane];
                    if (mx) {
                        int b2 = __builtin_amdgcn_readfirstlane(__builtin_ctzll(mx)); mx &= mx - 1;
                        v2f w2 = ((const v2f*)(W1t + (2 * b2) * HID))[lane];
                        if (mx) {
                            int b3i = __builtin_amdgcn_readfirstlane(__builtin_ctzll(mx)); mx &= mx - 1;
                            v2f w3 = ((const v2f*)(W1t + (2 * b3i) * HID))[lane];
                            cb += w3;
                        }
                        ca += w2;
                    }
                    cb += w1;
                }
                ca += w0;
            }
            while (my) {
                int b0 = __builtin_amdgcn_readfirstlane(__builtin_ctzll(my)); my &= my - 1;
                v2f w0 = ((const v2f*)(W1t + (2 * b0 + 1) * HID))[lane];
                if (my) {
                    int b1 = __builtin_amdgcn_readfirstlane(__builtin_ctzll(my)); my &= my - 1;
                    v2f w1 = ((const v2f*)(W1t + (2 * b1 + 1) * HID))[lane];
                    if (my) {
                        int b2 = __builtin_amdgcn_readfirstlane(__builtin_ctzll(my)); my &= my - 1;
                        v2f w2 = ((const v2f*)(W1t + (2 * b2 + 1) * HID))[lane];
                        if (my) {
                            int b3i = __builtin_amdgcn_readfirstlane(__builtin_ctzll(my)); my &= my - 1;
                            v2f w3 = ((const v2f*)(W1t + (2 * b3i + 1) * HID))[lane];
                            cb += w3;
                        }
                        ca += w2;
                    }
                    cb += w1;
                }
                ca += w0;
            }
            t1 += ca + cb;
        }
        // ---- layer1 spikes -> layer2 (4-peeled) ----
        {
            bool px = (t1.x >= 1.0f), py = (t1.y >= 1.0f);
            ull mx = __ballot(px);
            ull my = __ballot(py);
            if (px) t1.x -= 1.0f;
            if (py) t1.y -= 1.0f;
            v2f ca = (v2f)(0.f), cb = (v2f)(0.f);
            while (mx) {
                int b0 = __builtin_amdgcn_readfirstlane(__builtin_ctzll(mx)); mx &= mx - 1;
                v2f w0 = ((const v2f*)(W2t + (2 * b0) * HID))[lane];
                if (mx) {
                    int b1 = __builtin_amdgcn_readfirstlane(__builtin_ctzll(mx)); mx &= mx - 1;
                    v2f w1 = ((const v2f*)(W2t + (2 * b1) * HID))[lane];
                    if (mx) {
                        int b2 = __builtin_amdgcn_readfirstlane(__builtin_ctzll(mx)); mx &= mx - 1;
                        v2f w2 = ((const v2f*)(W2t + (2 * b2) * HID))[lane];
                        if (mx) {
                            int b3i = __builtin_amdgcn_readfirstlane(__builtin_ctzll(mx)); mx &= mx - 1;
                            v2f w3 = ((const v2f*)(W2t + (2 * b3i) * HID))[lane];
                            cb += w3;
                        }
                        ca += w2;
                    }
                    cb += w1;
                }
                ca += w0;
            }
            while (my) {
                int b0 = __builtin_amdgcn_readfirstlane(__builtin_ctzll(my)); my &= my - 1;
                v2f w0 = ((const v2f*)(W2t + (2 * b0 + 1) * HID))[lane];
                if (my) {
                    int b1 = __builtin_amdgcn_readfirstlane(__builtin_ctzll(my)); my &= my - 1;
                    v2f w1 = ((const v2f*)(W2t + (2 * b1 + 1) * HID))[lane];
                    if (my) {
                        int b2 = __builtin_amdgcn_readfirstlane(__builtin_ctzll(my)); my &= my - 1;
                        v2f w2 = ((const v2f*)(W2t + (2 * b2 + 1) * HID))[lane];
                        if (my) {
                            int b3i = __builtin_amdgcn_readfirstlane(__builtin_ctzll(my)); my &= my - 1;
                            v2f w3 = ((const v2f*)(W2t + (2 * b3i + 1) * HID))[lane];
                            cb += w3;
                        }
                        ca += w2;
                    }
                    cb += w1;
                }
                ca += w0;
            }
            t2 += ca + cb;
        }
        // ---- layer2 spikes -> layer3 (2-peeled spikes x 4-wide loads) ----
        {
            bool px = (t2.x >= 1.0f), py = (t2.y >= 1.0f);
            ull mx = __ballot(px);
            ull my = __ballot(py);
            if (px) t2.x -= 1.0f;
            if (py) t2.y -= 1.0f;
            while (mx) {
                int b0 = __builtin_amdgcn_readfirstlane(__builtin_ctzll(mx)); mx &= mx - 1;
                const v4f* c0 = (const v4f*)(W3t + (2 * b0) * IN_DIM);
                v4f x0 = c0[lane], x1 = c0[64 + lane], x2 = c0[128 + lane];
                v4f x3 = c0[192 + (lane & 3)];
                if (mx) {
                    int b1 = __builtin_amdgcn_readfirstlane(__builtin_ctzll(mx)); mx &= mx - 1;
                    const v4f* c1 = (const v4f*)(W3t + (2 * b1) * IN_DIM);
                    v4f y0 = c1[lane], y1 = c1[64 + lane], y2 = c1[128 + lane];
                    v4f y3 = c1[192 + (lane & 3)];
                    t3[0] += y0; t3[1] += y1; t3[2] += y2;
                    if (lane < 4) t3[3] += y3;
                }
                t3[0] += x0; t3[1] += x1; t3[2] += x2;
                if (lane < 4) t3[3] += x3;
            }
            while (my) {
                int b0 = __builtin_amdgcn_readfirstlane(__builtin_ctzll(my)); my &= my - 1;
                const v4f* c0 = (const v4f*)(W3t + (2 * b0 + 1) * IN_DIM);
                v4f x0 = c0[lane], x1 = c0[64 + lane], x2 = c0[128 + lane];
                v4f x3 = c0[192 + (lane & 3)];
                if (my) {
                    int b1 = __builtin_amdgcn_readfirstlane(__builtin_ctzll(my)); my &= my - 1;
                    const v4f* c1 = (const v4f*)(W3t + (2 * b1 + 1) * IN_DIM);
                    v4f y0 = c1[lane], y1 = c1[64 + lane], y2 = c1[128 + lane];
                    v4f y3 = c1[192 + (lane & 3)];
                    t3[0] += y0; t3[1] += y1; t3[2] += y2;
                    if (lane < 4) t3[3] += y3;
                }
                t3[0] += x0; t3[1] += x1; t3[2] += x2;
                if (lane < 4) t3[3] += x3;
            }
        }
        // ---- layer3 spike + output count ----
#pragma unroll
        for (int r = 0; r < 4; ++r) {
            if (t3[r].x >= 1.0f) { t3[r].x -= 1.0f; cnt[r].x += 1.0f; }
            if (t3[r].y >= 1.0f) { t3[r].y -= 1.0f; cnt[r].y += 1.0f; }
            if (t3[r].z >= 1.0f) { t3[r].z -= 1.0f; cnt[r].z += 1.0f; }
            if (t3[r].w >= 1.0f) { t3[r].w -= 1.0f; cnt[r].w += 1.0f; }
        }
    }

    // ---- reconstruct: spikes * h_out3 ----
    const float h = ob3[1] - ob3[0];
    v4f* orow = (v4f*)(out + (size_t)sample * IN_DIM);
#pragma unroll
    for (int r = 0; r < 3; ++r)
        orow[r * 64 + lane] = cnt[r] * h;
    if (lane < 4)
        orow[192 + lane] = cnt[3] * h;
}

extern "C" void kernel_launch(void* const* d_in, const int* in_sizes, int n_in,
                              void* d_out, int out_size, void* d_ws, size_t ws_size,
                              hipStream_t stream)
{
    const float* feat = (const float*)d_in[0];
    const float* W0  = (const float*)d_in[1];
    const float* b0  = (const float*)d_in[2];
    const float* W1  = (const float*)d_in[3];
    const float* b1  = (const float*)d_in[4];
    const float* W2  = (const float*)d_in[5];
    const float* b2  = (const float*)d_in[6];
    const float* W3  = (const float*)d_in[7];
    const float* b3  = (const float*)d_in[8];
    const float* ib0 = (const float*)d_in[9];
    const float* ob0 = (const float*)d_in[10];
    const float* ib1 = (const float*)d_in[11];
    const float* ob1 = (const float*)d_in[12];
    const float* ib2 = (const float*)d_in[13];
    const float* ob2 = (const float*)d_in[14];
    const float* ib3 = (const float*)d_in[15];
    const float* ob3 = (const float*)d_in[16];
    float* ws  = (float*)d_ws;
    float* op  = (float*)d_out;

    prep_kernel<<<(WS_FLOATS + 255) / 256, 256, 0, stream>>>(
        W0, b0, W1, b1, W2, b2, W3, b3,
        ib0, ob0, ib1, ob1, ib2, ob2, ib3, ob3, ws);

    snn_main<<<BATCH / WAVES, TPB, 0, stream>>>(feat, ws, ib0, ob3, op);
}